// Round 1
// baseline (206.787 us; speedup 1.0000x reference)
//
#include <hip/hip_runtime.h>

#define LAMBDA_COORD 5.0f
#define LAMBDA_NOOBJ 0.5f
#define DD 30
#define CELLS 256
#define BLOCK 256
#define F4_PER_INPUT (CELLS * DD / 4)   // 1920 float4 per input per block
#define FULL_ITERS (F4_PER_INPUT / BLOCK) // 7 (then a half-iteration)

__device__ __forceinline__ float iou_t(float tx, float ty, float tw, float th,
                                       float px, float py, float pw, float ph) {
    float xl = fmaxf(tx - tw * 0.5f, px - pw * 0.5f);
    float yt = fmaxf(ty - th * 0.5f, py - ph * 0.5f);
    float xr = fminf(tx + tw * 0.5f, px + pw * 0.5f);
    float yb = fminf(ty + th * 0.5f, py + ph * 0.5f);
    bool valid = (xr >= xl) && (yb >= yt);
    float inter = (xr - xl) * (yb - yt);
    float uni = tw * th + pw * ph - inter;
    float safe = (uni == 0.0f) ? 1.0f : uni;
    return valid ? (inter / safe) : 0.0f;
}

__global__ __launch_bounds__(BLOCK) void yolo_loss_kernel(
    const float* __restrict__ pred, const float* __restrict__ targ,
    float* __restrict__ out) {
    __shared__ __align__(16) float sp[CELLS * DD];
    __shared__ __align__(16) float st[CELLS * DD];
    __shared__ float wpart[BLOCK / 64];

    const int tid = threadIdx.x;
    const size_t base = (size_t)blockIdx.x * (CELLS * DD);

    // ---- coalesced float4 staging: global -> LDS ----
    const float4* gp = (const float4*)(pred + base);
    const float4* gt = (const float4*)(targ + base);
    float4* lp = (float4*)sp;
    float4* lt = (float4*)st;
#pragma unroll
    for (int i = 0; i < FULL_ITERS; ++i) {
        lp[tid + i * BLOCK] = gp[tid + i * BLOCK];
        lt[tid + i * BLOCK] = gt[tid + i * BLOCK];
    }
    {
        int i = tid + FULL_ITERS * BLOCK;   // tail: 1792..1919 (tid < 128)
        if (i < F4_PER_INPUT) { lp[i] = gp[i]; lt[i] = gt[i]; }
    }
    __syncthreads();

    // ---- per-cell loss from LDS ----
    const float* p = &sp[tid * DD];
    const float* t = &st[tid * DD];

    float t4 = t[4];
    float obj = (t4 > 0.0f) ? 1.0f : 0.0f;
    float noobj = (t4 == 0.0f) ? 1.0f : 0.0f;

    float cls = 0.0f;
#pragma unroll
    for (int k = 10; k < 30; ++k) {
        float d = t[k] - p[k];
        cls += d * d;
    }
    cls *= obj;

    float d4 = t4 - p[4];
    float conf_noobj = noobj * d4 * d4;

    float tx = t[0], ty = t[1], tw = t[2], th = t[3];
    float iou1 = iou_t(tx, ty, tw, th, p[0], p[1], p[2], p[3]);
    float iou2 = iou_t(tx, ty, tw, th, p[5], p[6], p[7], p[8]);
    float resp1 = (iou1 > iou2) ? 1.0f : 0.0f;
    float m1 = obj * resp1;
    float m2 = obj * (1.0f - resp1);

    float e1 = iou1 - p[4];
    float e2 = iou2 - p[9];
    float conf_obj = m1 * e1 * e1 + m2 * e2 * e2;

    float dx1 = tx - p[0], dy1 = ty - p[1];
    float dx2 = tx - p[5], dy2 = ty - p[6];
    float xy = m1 * (dx1 * dx1 + dy1 * dy1) + m2 * (dx2 * dx2 + dy2 * dy2);

    float dw1 = tw - p[2], dh1 = th - p[3];
    float dw2 = tw - p[7], dh2 = th - p[8];
    float wh = m1 * (dw1 * dw1 + dh1 * dh1) + m2 * (dw2 * dw2 + dh2 * dh2);

    float loss = LAMBDA_COORD * (xy + wh) + conf_obj + LAMBDA_NOOBJ * conf_noobj + cls;

    // ---- wave (64-lane) shuffle reduction ----
#pragma unroll
    for (int off = 32; off > 0; off >>= 1) loss += __shfl_down(loss, off);
    if ((tid & 63) == 0) wpart[tid >> 6] = loss;
    __syncthreads();
    if (tid == 0) {
        float s = wpart[0] + wpart[1] + wpart[2] + wpart[3];
        atomicAdd(out, s * (1.0f / 16384.0f));
    }
}

extern "C" void kernel_launch(void* const* d_in, const int* in_sizes, int n_in,
                              void* d_out, int out_size, void* d_ws, size_t ws_size,
                              hipStream_t stream) {
    const float* pred = (const float*)d_in[0];  // y
    const float* targ = (const float*)d_in[1];  // gt
    float* out = (float*)d_out;

    hipMemsetAsync(out, 0, sizeof(float), stream);

    const int cells = in_sizes[0] / DD;       // 802816
    const int grid = cells / CELLS;           // 3136 (exact)
    yolo_loss_kernel<<<grid, BLOCK, 0, stream>>>(pred, targ, out);
}